// Round 8
// baseline (54335.126 us; speedup 1.0000x reference)
//
#include <hip/hip_runtime.h>
#include <hip/hip_bf16.h>
#include <stdint.h>
#include <stddef.h>

using bf16_t = __hip_bfloat16;
typedef __attribute__((ext_vector_type(8))) short short8;
typedef __attribute__((ext_vector_type(4))) float f32x4;

// async global->LDS 16B copy (wave-uniform LDS base + lane*16 dest pattern)
__device__ __forceinline__ void gload_lds16(void* lds, const void* g) {
  __builtin_amdgcn_global_load_lds(
      (const __attribute__((address_space(1))) unsigned int*)g,
      (__attribute__((address_space(3))) unsigned int*)lds,
      16, 0, 0);
}

constexpr int BATCH = 4096, DATA = 512, HID = 1024;
constexpr int NBLK  = 512;     // 8 groups x 64 blocks; 2 blocks/CU
constexpr int BPG   = 64;      // blocks per group
constexpr int GROWS = 512;     // batch rows per group (4096/8)

struct MegaArgs {
  const float *x, *W1, *b1, *W2, *b2, *W3, *b3;
  float* y; bf16_t *yb, *zb, *h1, *h2;
  bf16_t *k1, *k2, *k3, *k4, *k5;
  bf16_t *W1b, *W2b, *W3b;
  float* out;
  unsigned* bar;               // 8 counters, 256B apart (zeroed per call)
};

struct Smem { bf16_t As[2][64 * 64]; bf16_t Bs[2][64 * 64]; };  // 32 KB

// ---------------------------------------------------------------------------
// Block j (of a 64-block group) computes nvt 64x64 tiles of
// C[GROWS x N] = A_group[GROWS x K] * B[N x K]^T  (A pre-offset to group rows).
// r6-proven core: 2-buffer LDS ring, depth-1 prefetch, 1 s_barrier/K-step,
// 16B-chunk XOR swizzle (slot s^(row&7)) via pre-swizzled global source.
// ---------------------------------------------------------------------------
template<bool COMB>
__device__ __forceinline__ void vgemm(
    Smem& sm, int j,
    const bf16_t* __restrict__ A, const bf16_t* __restrict__ B,
    const float* __restrict__ bias,
    bf16_t* __restrict__ obf,
    bf16_t* __restrict__ kdst,
    const float* __restrict__ yv, float* __restrict__ ywr,
    float* __restrict__ dout,
    const bf16_t* kp0, const bf16_t* kp1, const bf16_t* kp2, const bf16_t* kp3,
    float c0, float c1, float c2, float c3, float ccur,
    int K, int lgN, int nvt, int N, int lgnt)
{
  const int t    = threadIdx.x;
  const int lane = t & 63;
  const int wid  = t >> 6;
  const int wm   = wid >> 1;
  const int wn   = wid & 1;
  const int nt    = 1 << lgnt;          // K/64
  const int total = nvt << lgnt;
  const int nmask = (1 << lgN) - 1;
  const int ro = lane & 15;
  const int ks = lane >> 4;

  auto stage = [&](int b, int gi) {
    const int vt = j * nvt + (gi >> lgnt);
    const int kt = gi & (nt - 1);
    const bf16_t* Ag = A + (size_t)((vt >> lgN) * 64) * K + kt * 64;
    const bf16_t* Bg = B + (size_t)((vt & nmask) * 64) * K + kt * 64;
#pragma unroll
    for (int r = 0; r < 2; ++r) {
      int ch = t + r * 256, row = ch >> 3, s = ch & 7, sl = s ^ (row & 7);
      gload_lds16(&sm.As[b][ch * 8], Ag + (size_t)row * K + sl * 8);
    }
#pragma unroll
    for (int r = 0; r < 2; ++r) {
      int ch = t + r * 256, row = ch >> 3, s = ch & 7, sl = s ^ (row & 7);
      gload_lds16(&sm.Bs[b][ch * 8], Bg + (size_t)row * K + sl * 8);
    }
  };

  f32x4 acc[2][2] = {};
  stage(0, 0);

  for (int gi = 0; gi < total; ++gi) {
    const int c = gi & 1;
    asm volatile("s_waitcnt vmcnt(0)" ::: "memory");
    __builtin_amdgcn_s_barrier();
    asm volatile("" ::: "memory");
    if (gi + 1 < total) stage(c ^ 1, gi + 1);

#pragma unroll
    for (int kk = 0; kk < 2; ++kk) {
      short8 af[2], bfr[2];
      const int slot = kk * 4 + ks;
#pragma unroll
      for (int mi = 0; mi < 2; ++mi) {
        int row = wm * 32 + mi * 16 + ro;
        int ch  = row * 8 + (slot ^ (row & 7));
        af[mi]  = *(const short8*)&sm.As[c][ch * 8];
      }
#pragma unroll
      for (int ni = 0; ni < 2; ++ni) {
        int row = wn * 32 + ni * 16 + ro;
        int ch  = row * 8 + (slot ^ (row & 7));
        bfr[ni] = *(const short8*)&sm.Bs[c][ch * 8];
      }
      __builtin_amdgcn_s_setprio(1);
#pragma unroll
      for (int mi = 0; mi < 2; ++mi)
#pragma unroll
        for (int ni = 0; ni < 2; ++ni)
          acc[mi][ni] = __builtin_amdgcn_mfma_f32_16x16x32_bf16(
              af[mi], bfr[ni], acc[mi][ni], 0, 0, 0);
      __builtin_amdgcn_s_setprio(0);
    }

    if (((gi + 1) & (nt - 1)) == 0) {   // virtual tile done -> epilogue
      const int vt = j * nvt + (gi >> lgnt);
      const int rb = (vt >> lgN) * 64 + wm * 32;
      const int cb = (vt & nmask) * 64 + wn * 32;
#pragma unroll
      for (int mi = 0; mi < 2; ++mi) {
#pragma unroll
        for (int ni = 0; ni < 2; ++ni) {
          const int col = cb + ni * 16 + ro;
          const float bv = bias[col];
#pragma unroll
          for (int r = 0; r < 4; ++r) {
            const int row = rb + mi * 16 + (lane >> 4) * 4 + r;
            const size_t idx = (size_t)row * N + col;
            float v = acc[mi][ni][r] + bv;
            if (COMB) {
              if (kdst) kdst[idx] = __float2bfloat16(v);
              float z = yv[idx] + ccur * v;
              if (kp0) z += c0 * __bfloat162float(kp0[idx]);
              if (kp1) z += c1 * __bfloat162float(kp1[idx]);
              if (kp2) z += c2 * __bfloat162float(kp2[idx]);
              if (kp3) z += c3 * __bfloat162float(kp3[idx]);
              if (ywr)  ywr[idx]  = z;
              if (dout) dout[idx] = z;
              obf[idx] = __float2bfloat16(z);
            } else {
              obf[idx] = __float2bfloat16(fmaxf(v, 0.f));
            }
          }
          acc[mi][ni] = f32x4{0.f, 0.f, 0.f, 0.f};
        }
      }
    }
  }
}

// ---------------------------------------------------------------------------
__global__ void __launch_bounds__(256, 2) ode_mega(MegaArgs a) {
  __shared__ Smem sm;
  const int bid = blockIdx.x;
  const int g   = bid & 7;         // group (expected XCD under round-robin)
  const int j   = bid >> 3;        // member 0..63
  unsigned* ctr = a.bar + (size_t)g * 64;   // 256B-separated counters
  unsigned phase = 0;

  // 64-block group barrier: monotonic counter, agent-scope fences.
  auto gbar = [&]() {
    __syncthreads();
    ++phase;
    if (threadIdx.x == 0) {
      __threadfence();   // release: group's stores visible at agent scope
      __hip_atomic_fetch_add(ctr, 1u, __ATOMIC_RELAXED, __HIP_MEMORY_SCOPE_AGENT);
      while (__hip_atomic_load(ctr, __ATOMIC_RELAXED, __HIP_MEMORY_SCOPE_AGENT)
             < phase * (unsigned)BPG)
        __builtin_amdgcn_s_sleep(2);
      __threadfence();   // acquire: invalidate stale L1/L2 lines
    }
    __syncthreads();
  };

  const size_t god = (size_t)g * GROWS * DATA;
  const size_t goh = (size_t)g * GROWS * HID;

  // ---- setup: weights f32->bf16 (redundant per group: identical duplicate
  // stores are benign), y/yb init for the group's rows ----
  {
    const int gt = j * 256 + (int)threadIdx.x;   // [0, 16384) within group
    const int gs = BPG * 256;
    auto cvt4 = [&](const float* in, bf16_t* outp, int n) {
      for (int i = gt * 4; i < n; i += gs * 4) {
        float4 v = *(const float4*)(in + i);
        bf16_t o[4] = {__float2bfloat16(v.x), __float2bfloat16(v.y),
                       __float2bfloat16(v.z), __float2bfloat16(v.w)};
        *(uint64_t*)(outp + i) = *(uint64_t*)o;
      }
    };
    cvt4(a.W1, a.W1b, HID * DATA);
    cvt4(a.W2, a.W2b, HID * HID);
    cvt4(a.W3, a.W3b, DATA * HID);
    const float* xg = a.x + god;
    float* yg = a.y + god;
    bf16_t* ybg = a.yb + god;
    for (int i = gt * 4; i < GROWS * DATA; i += gs * 4) {
      float4 v = *(const float4*)(xg + i);
      *(float4*)(yg + i) = v;
      bf16_t o[4] = {__float2bfloat16(v.x), __float2bfloat16(v.y),
                     __float2bfloat16(v.z), __float2bfloat16(v.w)};
      *(uint64_t*)(ybg + i) = *(uint64_t*)o;
    }
  }
  gbar();

  // ---- dopri5 tableau (times h = 1/64) ----
  constexpr double hh = 1.0 / 64.0;
  constexpr float hA21 = (float)(hh * (1.0/5.0));
  constexpr float hA31 = (float)(hh * (3.0/40.0)),   hA32 = (float)(hh * (9.0/40.0));
  constexpr float hA41 = (float)(hh * (44.0/45.0)),  hA42 = (float)(hh * (-56.0/15.0)),
                  hA43 = (float)(hh * (32.0/9.0));
  constexpr float hA51 = (float)(hh * (19372.0/6561.0)), hA52 = (float)(hh * (-25360.0/2187.0)),
                  hA53 = (float)(hh * (64448.0/6561.0)), hA54 = (float)(hh * (-212.0/729.0));
  constexpr float hA61 = (float)(hh * (9017.0/3168.0)),  hA62 = (float)(hh * (-355.0/33.0)),
                  hA63 = (float)(hh * (46732.0/5247.0)), hA64 = (float)(hh * (49.0/176.0)),
                  hA65 = (float)(hh * (-5103.0/18656.0));
  constexpr float hB1 = (float)(hh * (35.0/384.0)),  hB3 = (float)(hh * (500.0/1113.0)),
                  hB4 = (float)(hh * (125.0/192.0)), hB5 = (float)(hh * (-2187.0/6784.0)),
                  hB6 = (float)(hh * (11.0/84.0));

  for (int step = 0; step < 64; ++step) {
    for (int s = 0; s < 6; ++s) {
      const bf16_t* zin = ((s == 0) ? a.yb : a.zb) + god;

      // GEMM1: h1 = relu(zin @ W1^T + b1)   [GROWS x 1024, K=512]
      vgemm<false>(sm, j, zin, a.W1b, a.b1, a.h1 + goh,
                   nullptr, nullptr, nullptr, nullptr,
                   nullptr, nullptr, nullptr, nullptr,
                   0.f, 0.f, 0.f, 0.f, 0.f,
                   DATA, 4, 2, HID, 3);
      gbar();

      // GEMM2: h2 = relu(h1 @ W2^T + b2)    [GROWS x 1024, K=1024]
      vgemm<false>(sm, j, a.h1 + goh, a.W2b, a.b2, a.h2 + goh,
                   nullptr, nullptr, nullptr, nullptr,
                   nullptr, nullptr, nullptr, nullptr,
                   0.f, 0.f, 0.f, 0.f, 0.f,
                   HID, 4, 2, HID, 4);
      gbar();

      // GEMM3 + RK combine                  [GROWS x 512, K=1024]
      const bf16_t *p0 = nullptr, *p1 = nullptr, *p2 = nullptr, *p3 = nullptr;
      float c0 = 0.f, c1 = 0.f, c2 = 0.f, c3 = 0.f, ccur;
      bf16_t* kd = nullptr;
      switch (s) {
        case 0: ccur = hA21; kd = a.k1 + god; break;
        case 1: ccur = hA32; kd = a.k2 + god; p0 = a.k1 + god; c0 = hA31; break;
        case 2: ccur = hA43; kd = a.k3 + god; p0 = a.k1 + god; c0 = hA41;
                p1 = a.k2 + god; c1 = hA42; break;
        case 3: ccur = hA54; kd = a.k4 + god; p0 = a.k1 + god; c0 = hA51;
                p1 = a.k2 + god; c1 = hA52; p2 = a.k3 + god; c2 = hA53; break;
        case 4: ccur = hA65; kd = a.k5 + god; p0 = a.k1 + god; c0 = hA61;
                p1 = a.k2 + god; c1 = hA62; p2 = a.k3 + god; c2 = hA63;
                p3 = a.k4 + god; c3 = hA64; break;
        default: ccur = hB6; p0 = a.k1 + god; c0 = hB1; p1 = a.k3 + god; c1 = hB3;
                 p2 = a.k4 + god; c2 = hB4; p3 = a.k5 + god; c3 = hB5; break;
      }
      bf16_t* ob  = ((s == 5) ? a.yb : a.zb) + god;
      float*  ywr = (s == 5) ? a.y + god : nullptr;
      float*  dst = (s == 5 && step == 63) ? a.out + god : nullptr;
      vgemm<true>(sm, j, a.h2 + goh, a.W3b, a.b3, ob,
                  kd, a.y + god, ywr, dst,
                  p0, p1, p2, p3, c0, c1, c2, c3, ccur,
                  HID, 3, 1, DATA, 4);
      gbar();
    }
  }
}

// ---------------------------------------------------------------------------
extern "C" void kernel_launch(void* const* d_in, const int* in_sizes, int n_in,
                              void* d_out, int out_size, void* d_ws, size_t ws_size,
                              hipStream_t stream)
{
  char* ws = (char*)d_ws;
  size_t off = 0;
  auto alloc = [&](size_t bytes) -> void* {
    off = (off + 255) & ~(size_t)255;
    void* p = ws + off;
    off += bytes;
    return p;
  };
  const size_t nyd = (size_t)BATCH * DATA;
  const size_t nh  = (size_t)BATCH * HID;

  MegaArgs a;
  a.bar = (unsigned*)alloc(4096);          // 8 counters, 256B apart
  a.x  = (const float*)d_in[0];
  a.W1 = (const float*)d_in[1];
  a.b1 = (const float*)d_in[2];
  a.W2 = (const float*)d_in[3];
  a.b2 = (const float*)d_in[4];
  a.W3 = (const float*)d_in[5];
  a.b3 = (const float*)d_in[6];

  a.y   = (float*)alloc(nyd * 4);
  a.yb  = (bf16_t*)alloc(nyd * 2);
  a.zb  = (bf16_t*)alloc(nyd * 2);
  a.h1  = (bf16_t*)alloc(nh * 2);
  a.h2  = (bf16_t*)alloc(nh * 2);
  a.k1  = (bf16_t*)alloc(nyd * 2);
  a.k2  = (bf16_t*)alloc(nyd * 2);
  a.k3  = (bf16_t*)alloc(nyd * 2);
  a.k4  = (bf16_t*)alloc(nyd * 2);
  a.k5  = (bf16_t*)alloc(nyd * 2);
  a.W1b = (bf16_t*)alloc((size_t)HID * DATA * 2);
  a.W2b = (bf16_t*)alloc((size_t)HID * HID * 2);
  a.W3b = (bf16_t*)alloc((size_t)DATA * HID * 2);
  a.out = (float*)d_out;

  hipMemsetAsync(a.bar, 0, 4096, stream);  // barrier counters start at 0
  ode_mega<<<dim3(NBLK), dim3(256), 0, stream>>>(a);
}

// Round 9
// 18222.298 us; speedup vs baseline: 2.9818x; 2.9818x over previous
//
#include <hip/hip_runtime.h>
#include <hip/hip_bf16.h>
#include <stdint.h>
#include <stddef.h>

using bf16_t = __hip_bfloat16;
typedef __attribute__((ext_vector_type(8))) short short8;
typedef __attribute__((ext_vector_type(4))) float f32x4;

// async global->LDS 16B copy (wave-uniform LDS base + lane*16 dest pattern)
__device__ __forceinline__ void gload_lds16(void* lds, const void* g) {
  __builtin_amdgcn_global_load_lds(
      (const __attribute__((address_space(1))) unsigned int*)g,
      (__attribute__((address_space(3))) unsigned int*)lds,
      16, 0, 0);
}

// ---------------------------------------------------------------------------
// GEMM  C[m][n] = sum_k A[m][k] * B[n][k]   (A: MxK bf16, B: NxK bf16)
// BM=BN=64, BK=64. 4 waves (2x2), wave tile 32x32, 256 threads.
// 2-buffer LDS ring (32 KB/block -> 4 blocks/CU, 16 waves/CU), depth-1
// prefetch, 1 s_barrier per K-step:
//   [wait vmcnt(0)] [barrier] [stage t+1 -> other buf] [setprio MFMA]
// LDS 16B-chunk XOR swizzle (slot s^(row&7)) via pre-swizzled global source.
// 1-D grid, XCD-bijective swizzle (T1): nwg % 8 == 0. Batch rows partition
// as [xcd*M/8, (xcd+1)*M/8) for every GEMM -> producer/consumer L2-local.
//
// MODE 0: obf = bf16(relu(acc + bias))                    (hidden layers)
// MODE 1: k = acc+bias; kout=bf16(k); z = y + ccur*k + sum c_j*k_j; obf=bf16(z)
// MODE 2: z = y + ccur*k + sum c_j*k_j; yf_out=z (fp32); obf=bf16(z)
// (MODE is a single template arg so the mangled name has no comma ->
//  rocprof CSV stays parseable; that bug hid all counters in rounds 1-6.)
// ---------------------------------------------------------------------------
template<int MODE>
__global__ __launch_bounds__(256, 4)
void gemm_bt(const bf16_t* __restrict__ A, const bf16_t* __restrict__ B,
             const float* __restrict__ bias,
             bf16_t* __restrict__ obf,
             bf16_t* __restrict__ kout,
             float* __restrict__ yf_out,
             const float* __restrict__ y_in,
             const bf16_t* __restrict__ kp0, const bf16_t* __restrict__ kp1,
             const bf16_t* __restrict__ kp2, const bf16_t* __restrict__ kp3,
             float c0, float c1, float c2, float c3, float ccur,
             int M, int N, int K, int lgx)
{
  __shared__ __align__(16) bf16_t As[2][64 * 64];
  __shared__ __align__(16) bf16_t Bs[2][64 * 64];

  const int t    = threadIdx.x;
  const int lane = t & 63;
  const int wid  = t >> 6;
  const int wm   = wid >> 1;   // 0..1
  const int wn   = wid & 1;    // 0..1

  const int nwg = gridDim.x, bid = blockIdx.x;
  const int swz = (bid & 7) * (nwg >> 3) + (bid >> 3);
  const int gxm = (1 << lgx) - 1;
  const int bx  = swz & gxm;
  const int by  = swz >> lgx;
  const int bn0 = bx * 64, bm0 = by * 64;

  const bf16_t* Ag = A + (size_t)bm0 * K;
  const bf16_t* Bg = B + (size_t)bn0 * K;

  f32x4 acc[2][2] = {};

  // stage tile kt into buffer b; chunk(row,s) holds logical slot s^(row&7)
  auto stage = [&](int b, int kt) {
    const int k0 = kt * 64;
#pragma unroll
    for (int r = 0; r < 2; ++r) {           // A: 64*8=512 chunks, 2 rounds
      int ch  = t + r * 256;
      int row = ch >> 3, s = ch & 7;
      int sl  = s ^ (row & 7);
      gload_lds16(&As[b][ch * 8], Ag + (size_t)row * K + k0 + sl * 8);
    }
#pragma unroll
    for (int r = 0; r < 2; ++r) {           // B: 2 rounds
      int ch  = t + r * 256;
      int row = ch >> 3, s = ch & 7;
      int sl  = s ^ (row & 7);
      gload_lds16(&Bs[b][ch * 8], Bg + (size_t)row * K + k0 + sl * 8);
    }
  };

  const int nt = K >> 6;
  stage(0, 0);

  const int ro = lane & 15;
  const int ks = lane >> 4;

  for (int tt = 0; tt < nt; ++tt) {
    const int c = tt & 1;
    asm volatile("s_waitcnt vmcnt(0)" ::: "memory");
    __builtin_amdgcn_s_barrier();          // all waves done with buf c^1
    asm volatile("" ::: "memory");

    if (tt + 1 < nt) stage(c ^ 1, tt + 1); // issue next tile's loads early

#pragma unroll
    for (int kk = 0; kk < 2; ++kk) {
      short8 af[2], bfr[2];
      const int slot = kk * 4 + ks;
#pragma unroll
      for (int mi = 0; mi < 2; ++mi) {
        int row = wm * 32 + mi * 16 + ro;
        int ch  = row * 8 + (slot ^ (row & 7));
        af[mi]  = *(const short8*)&As[c][ch * 8];
      }
#pragma unroll
      for (int ni = 0; ni < 2; ++ni) {
        int row = wn * 32 + ni * 16 + ro;
        int ch  = row * 8 + (slot ^ (row & 7));
        bfr[ni] = *(const short8*)&Bs[c][ch * 8];
      }
      __builtin_amdgcn_s_setprio(1);
#pragma unroll
      for (int mi = 0; mi < 2; ++mi)
#pragma unroll
        for (int ni = 0; ni < 2; ++ni)
          acc[mi][ni] = __builtin_amdgcn_mfma_f32_16x16x32_bf16(
              af[mi], bfr[ni], acc[mi][ni], 0, 0, 0);
      __builtin_amdgcn_s_setprio(0);
    }
  }

  // ---- epilogue -----------------------------------------------------------
  const int rb = bm0 + wm * 32;
  const int cb = bn0 + wn * 32;
#pragma unroll
  for (int mi = 0; mi < 2; ++mi) {
#pragma unroll
    for (int ni = 0; ni < 2; ++ni) {
      const int col = cb + ni * 16 + ro;
      const float bv = bias[col];
#pragma unroll
      for (int r = 0; r < 4; ++r) {
        const int row = rb + mi * 16 + (lane >> 4) * 4 + r;
        const size_t idx = (size_t)row * N + col;
        float v = acc[mi][ni][r] + bv;
        if (MODE == 0) {
          obf[idx] = __float2bfloat16(fmaxf(v, 0.f));
        } else {
          if (MODE == 1) kout[idx] = __float2bfloat16(v);
          float z = y_in[idx] + ccur * v;
          if (kp0) z += c0 * __bfloat162float(kp0[idx]);
          if (kp1) z += c1 * __bfloat162float(kp1[idx]);
          if (kp2) z += c2 * __bfloat162float(kp2[idx]);
          if (kp3) z += c3 * __bfloat162float(kp3[idx]);
          if (MODE == 2) yf_out[idx] = z;
          obf[idx] = __float2bfloat16(z);
        }
      }
    }
  }
}

// ---------------------------------------------------------------------------
// single fused init: weights f32->bf16, y=x, yb=bf16(x)
// ---------------------------------------------------------------------------
__global__ void init_all(const float* __restrict__ x,
                         const float* __restrict__ W1,
                         const float* __restrict__ W2,
                         const float* __restrict__ W3,
                         bf16_t* __restrict__ W1b, bf16_t* __restrict__ W2b,
                         bf16_t* __restrict__ W3b,
                         float* __restrict__ y, bf16_t* __restrict__ yb,
                         int n1, int n2, int n3, int ny)
{
  const int gt = blockIdx.x * blockDim.x + threadIdx.x;
  const int gs = gridDim.x * blockDim.x;
  auto cvt4 = [&](const float* in, bf16_t* outp, int n) {
    for (int i = gt * 4; i < n; i += gs * 4) {
      float4 v = *(const float4*)(in + i);
      bf16_t o[4] = {__float2bfloat16(v.x), __float2bfloat16(v.y),
                     __float2bfloat16(v.z), __float2bfloat16(v.w)};
      *(uint64_t*)(outp + i) = *(uint64_t*)o;
    }
  };
  cvt4(W1, W1b, n1);
  cvt4(W2, W2b, n2);
  cvt4(W3, W3b, n3);
  for (int i = gt * 4; i < ny; i += gs * 4) {
    float4 v = *(const float4*)(x + i);
    *(float4*)(y + i) = v;
    bf16_t o[4] = {__float2bfloat16(v.x), __float2bfloat16(v.y),
                   __float2bfloat16(v.z), __float2bfloat16(v.w)};
    *(uint64_t*)(yb + i) = *(uint64_t*)o;
  }
}

// ---------------------------------------------------------------------------
extern "C" void kernel_launch(void* const* d_in, const int* in_sizes, int n_in,
                              void* d_out, int out_size, void* d_ws, size_t ws_size,
                              hipStream_t stream)
{
  const float* x  = (const float*)d_in[0];
  const float* W1 = (const float*)d_in[1];
  const float* b1 = (const float*)d_in[2];
  const float* W2 = (const float*)d_in[3];
  const float* b2 = (const float*)d_in[4];
  const float* W3 = (const float*)d_in[5];
  const float* b3 = (const float*)d_in[6];

  const int data   = in_sizes[6];            // 512
  const int hidden = in_sizes[2];            // 1024
  const int batch  = in_sizes[0] / data;     // 4096

  char* ws = (char*)d_ws;
  size_t off = 0;
  auto alloc = [&](size_t bytes) -> void* {
    off = (off + 255) & ~(size_t)255;
    void* p = ws + off;
    off += bytes;
    return p;
  };
  const size_t nyd = (size_t)batch * data;
  const size_t nh  = (size_t)batch * hidden;

  float*  y   = (float*)alloc(nyd * 4);
  bf16_t* yb  = (bf16_t*)alloc(nyd * 2);
  bf16_t* zb  = (bf16_t*)alloc(nyd * 2);
  bf16_t* h1  = (bf16_t*)alloc(nh * 2);
  bf16_t* h2  = (bf16_t*)alloc(nh * 2);
  bf16_t* k1  = (bf16_t*)alloc(nyd * 2);
  bf16_t* k2  = (bf16_t*)alloc(nyd * 2);
  bf16_t* k3  = (bf16_t*)alloc(nyd * 2);
  bf16_t* k4  = (bf16_t*)alloc(nyd * 2);
  bf16_t* k5  = (bf16_t*)alloc(nyd * 2);
  bf16_t* W1b = (bf16_t*)alloc((size_t)hidden * data * 2);
  bf16_t* W2b = (bf16_t*)alloc((size_t)hidden * hidden * 2);
  bf16_t* W3b = (bf16_t*)alloc((size_t)data * hidden * 2);

  init_all<<<2048, 256, 0, stream>>>(x, W1, W2, W3, W1b, W2b, W3b, y, yb,
                                     hidden * data, hidden * hidden,
                                     data * hidden, (int)nyd);

  const double hh = 1.0 / 64.0;
  const float hA21 = (float)(hh * (1.0/5.0));
  const float hA31 = (float)(hh * (3.0/40.0)),    hA32 = (float)(hh * (9.0/40.0));
  const float hA41 = (float)(hh * (44.0/45.0)),   hA42 = (float)(hh * (-56.0/15.0)),
              hA43 = (float)(hh * (32.0/9.0));
  const float hA51 = (float)(hh * (19372.0/6561.0)),  hA52 = (float)(hh * (-25360.0/2187.0)),
              hA53 = (float)(hh * (64448.0/6561.0)),  hA54 = (float)(hh * (-212.0/729.0));
  const float hA61 = (float)(hh * (9017.0/3168.0)),   hA62 = (float)(hh * (-355.0/33.0)),
              hA63 = (float)(hh * (46732.0/5247.0)),  hA64 = (float)(hh * (49.0/176.0)),
              hA65 = (float)(hh * (-5103.0/18656.0));
  const float hB1 = (float)(hh * (35.0/384.0)),   hB3 = (float)(hh * (500.0/1113.0)),
              hB4 = (float)(hh * (125.0/192.0)),  hB5 = (float)(hh * (-2187.0/6784.0)),
              hB6 = (float)(hh * (11.0/84.0));

  const dim3 blk(256);
  const int gridH = (hidden / 64) * (batch / 64);   // 16*64 = 1024, lgx=4
  const int grid3 = (data / 64) * (batch / 64);     //  8*64 = 512,  lgx=3
  const int lgxH = 4, lgx3 = 3;

  auto mlp_front = [&](const bf16_t* zin) {
    gemm_bt<0><<<gridH, blk, 0, stream>>>(
        zin, W1b, b1, h1, nullptr, nullptr, nullptr,
        nullptr, nullptr, nullptr, nullptr, 0.f, 0.f, 0.f, 0.f, 0.f,
        batch, hidden, data, lgxH);
    gemm_bt<0><<<gridH, blk, 0, stream>>>(
        h1, W2b, b2, h2, nullptr, nullptr, nullptr,
        nullptr, nullptr, nullptr, nullptr, 0.f, 0.f, 0.f, 0.f, 0.f,
        batch, hidden, hidden, lgxH);
  };

  auto stage_k = [&](bf16_t* kout, const bf16_t* p0, float cc0, const bf16_t* p1, float cc1,
                     const bf16_t* p2, float cc2, const bf16_t* p3, float cc3, float ccur) {
    gemm_bt<1><<<grid3, blk, 0, stream>>>(
        h2, W3b, b3, zb, kout, nullptr, y,
        p0, p1, p2, p3, cc0, cc1, cc2, cc3, ccur,
        batch, data, hidden, lgx3);
  };

  for (int step = 0; step < 64; ++step) {
    mlp_front(yb);
    stage_k(k1, nullptr, 0.f, nullptr, 0.f, nullptr, 0.f, nullptr, 0.f, hA21);
    mlp_front(zb);
    stage_k(k2, k1, hA31, nullptr, 0.f, nullptr, 0.f, nullptr, 0.f, hA32);
    mlp_front(zb);
    stage_k(k3, k1, hA41, k2, hA42, nullptr, 0.f, nullptr, 0.f, hA43);
    mlp_front(zb);
    stage_k(k4, k1, hA51, k2, hA52, k3, hA53, nullptr, 0.f, hA54);
    mlp_front(zb);
    stage_k(k5, k1, hA61, k2, hA62, k3, hA63, k4, hA64, hA65);
    mlp_front(zb);
    float* yf = (step == 63) ? (float*)d_out : y;
    gemm_bt<2><<<grid3, blk, 0, stream>>>(
        h2, W3b, b3, yb, nullptr, yf, y,
        k1, k3, k4, k5, hB1, hB3, hB4, hB5, hB6,
        batch, data, hidden, lgx3);
  }
}